// Round 4
// baseline (326.752 us; speedup 1.0000x reference)
//
#include <hip/hip_runtime.h>
#include <math.h>

typedef float  f32x4 __attribute__((ext_vector_type(4)));
typedef short  s16x8 __attribute__((ext_vector_type(8)));
typedef unsigned short u16x4 __attribute__((ext_vector_type(4)));
typedef unsigned short u16x8 __attribute__((ext_vector_type(8)));

// ---------- helpers ----------
__device__ __forceinline__ unsigned short f2bf(float f) {
  unsigned u = __float_as_uint(f);
  u += 0x7FFFu + ((u >> 16) & 1u);   // round-to-nearest-even
  return (unsigned short)(u >> 16);
}
// monotone float->uint encoding, re-biased so enc2(-inf) == 0 (memset-friendly)
__device__ __forceinline__ unsigned fenc2(float f) {
  unsigned u = __float_as_uint(f);
  u = (u & 0x80000000u) ? ~u : (u | 0x80000000u);
  return u - 0x007FFFFFu;
}
__device__ __forceinline__ float fdec2(unsigned u) {
  u += 0x007FFFFFu;
  u = (u & 0x80000000u) ? (u & 0x7FFFFFFFu) : ~u;
  return __uint_as_float(u);
}
__device__ __forceinline__ void gload16(const void* g, void* l) {
  __builtin_amdgcn_global_load_lds(
      (const __attribute__((address_space(1))) unsigned int*)g,
      (__attribute__((address_space(3))) unsigned int*)l, 16, 0, 0);
}

// ---------- weights f32 -> bf16 (both in one launch) ----------
__global__ __launch_bounds__(256) void cvt2(const float* __restrict__ a,
                                            const float* __restrict__ b,
                                            unsigned short* __restrict__ da,
                                            unsigned short* __restrict__ db, int n4) {
  int i = blockIdx.x * 256 + threadIdx.x;
  int stride = gridDim.x * 256;
  for (; i < 2 * n4; i += stride) {
    const float* s = (i < n4) ? a : b;
    unsigned short* d = (i < n4) ? da : db;
    int j = (i < n4) ? i : i - n4;
    f32x4 v = ((const f32x4*)s)[j];
    u16x4 o;
    o[0] = f2bf(v[0]); o[1] = f2bf(v[1]); o[2] = f2bf(v[2]); o[3] = f2bf(v[3]);
    ((u16x4*)d)[j] = o;
  }
}

// ---------- proj: Out = bf16(Xf32 @ W^T + bias), ssq[row] += sum of squares ----------
// Double-buffered LDS, one barrier per K-step. A: f32 reg-stage issued EARLY (T14),
// cvt+swizzled ds_write after MFMA. B: global_load_lds with pre-swizzled source.
__global__ __launch_bounds__(256) void proj(const float* __restrict__ Xq,
                                            const float* __restrict__ Xk,
                                            const unsigned short* __restrict__ Wqb,
                                            const unsigned short* __restrict__ Wkb,
                                            const float* __restrict__ bq,
                                            const float* __restrict__ bk,
                                            unsigned short* __restrict__ Qh,
                                            unsigned short* __restrict__ Kh,
                                            float* __restrict__ qssq,
                                            float* __restrict__ kssq) {
  const int K = 768;
  __shared__ __align__(16) unsigned short sA[2][128 * 64];
  __shared__ __align__(16) unsigned short sB[2][128 * 64];
  int id = blockIdx.x;                 // 0..767
  int xcd = id & 7, j = id >> 3;       // j: 0..95
  int by = j % 6, bxl = j / 6;         // by 0..5, bxl 0..15
  int bx = xcd * 16 + bxl;             // 0..127
  const float* A; const unsigned short* Bw; const float* bias;
  unsigned short* Out; float* ssq;
  if (blockIdx.z == 0) { A = Xq; Bw = Wqb; bias = bq; Out = Qh; ssq = qssq; }
  else                 { A = Xk; Bw = Wkb; bias = bk; Out = Kh; ssq = kssq; }

  const int t = threadIdx.x;
  const int lane = t & 63, w = t >> 6;
  const int wr = w >> 1, wc = w & 1;
  const int m0 = bx * 128, n0 = by * 128;
  const float* Ab = A + (size_t)m0 * K;
  const unsigned short* Bb = Bw + (size_t)n0 * K;
  f32x4 acc[4][4] = {};
  const int srow = t >> 3;             // 0..31
  const int scol = (t & 7) * 8;        // halfword col offset in 64
  const int hsw = scol ^ ((srow & 7) << 3);
  const int lg = lane >> 4, li = lane & 15;

  // prologue: stage K-tile 0 into buffer 0
#pragma unroll
  for (int s = 0; s < 4; ++s) {
    int row = srow + s * 32;
    gload16(Bb + (size_t)row * K + hsw, (char*)sB[0] + t * 16 + s * 4096);
  }
  {
    f32x4 v0[4], v1[4];
#pragma unroll
    for (int s = 0; s < 4; ++s) {
      const float* src = Ab + (size_t)(srow + s * 32) * K + scol;
      v0[s] = *(const f32x4*)src; v1[s] = *(const f32x4*)(src + 4);
    }
#pragma unroll
    for (int s = 0; s < 4; ++s) {
      int row = srow + s * 32;
      u16x8 o;
      o[0] = f2bf(v0[s][0]); o[1] = f2bf(v0[s][1]); o[2] = f2bf(v0[s][2]); o[3] = f2bf(v0[s][3]);
      o[4] = f2bf(v1[s][0]); o[5] = f2bf(v1[s][1]); o[6] = f2bf(v1[s][2]); o[7] = f2bf(v1[s][3]);
      *(u16x8*)(sA[0] + row * 64 + (scol ^ ((row & 7) << 3))) = o;
    }
  }
  __syncthreads();

  for (int kt = 0; kt < 12; ++kt) {
    const int cur = kt & 1;
    const unsigned short* cA = sA[cur];
    const unsigned short* cB = sB[cur];
    f32x4 p0[4], p1[4];
    const bool pre = (kt < 11);
    if (pre) {
      const int k0n = (kt + 1) * 64;
#pragma unroll
      for (int s = 0; s < 4; ++s) {
        int row = srow + s * 32;
        gload16(Bb + (size_t)row * K + k0n + hsw, (char*)sB[cur ^ 1] + t * 16 + s * 4096);
      }
#pragma unroll
      for (int s = 0; s < 4; ++s) {
        const float* src = Ab + (size_t)(srow + s * 32) * K + k0n + scol;
        p0[s] = *(const f32x4*)src; p1[s] = *(const f32x4*)(src + 4);
      }
    }
    // compute current buffer
#pragma unroll
    for (int ks = 0; ks < 2; ++ks) {
      s16x8 af[4], bfr[4];
#pragma unroll
      for (int mi = 0; mi < 4; ++mi) {
        int row = wr * 64 + mi * 16 + li;
        af[mi] = *(const s16x8*)(cA + row * 64 + ((ks * 32 + lg * 8) ^ ((row & 7) << 3)));
      }
#pragma unroll
      for (int ni = 0; ni < 4; ++ni) {
        int row = wc * 64 + ni * 16 + li;
        bfr[ni] = *(const s16x8*)(cB + row * 64 + ((ks * 32 + lg * 8) ^ ((row & 7) << 3)));
      }
#pragma unroll
      for (int mi = 0; mi < 4; ++mi)
#pragma unroll
        for (int ni = 0; ni < 4; ++ni)
          acc[mi][ni] = __builtin_amdgcn_mfma_f32_16x16x32_bf16(af[mi], bfr[ni], acc[mi][ni], 0, 0, 0);
    }
    if (pre) {
#pragma unroll
      for (int s = 0; s < 4; ++s) {
        int row = srow + s * 32;
        u16x8 o;
        o[0] = f2bf(p0[s][0]); o[1] = f2bf(p0[s][1]); o[2] = f2bf(p0[s][2]); o[3] = f2bf(p0[s][3]);
        o[4] = f2bf(p1[s][0]); o[5] = f2bf(p1[s][1]); o[6] = f2bf(p1[s][2]); o[7] = f2bf(p1[s][3]);
        *(u16x8*)(sA[cur ^ 1] + row * 64 + (scol ^ ((row & 7) << 3))) = o;
      }
    }
    __syncthreads();
  }
  // epilogue: bias, bf16 store, per-row sum-of-squares -> atomicAdd
  float bv[4]; int col[4];
#pragma unroll
  for (int ni = 0; ni < 4; ++ni) { col[ni] = n0 + wc * 64 + ni * 16 + li; bv[ni] = bias[col[ni]]; }
#pragma unroll
  for (int mi = 0; mi < 4; ++mi) {
    int rbase = m0 + wr * 64 + mi * 16 + lg * 4;
#pragma unroll
    for (int r = 0; r < 4; ++r) {
      float s = 0.f;
#pragma unroll
      for (int ni = 0; ni < 4; ++ni) {
        float v = acc[mi][ni][r] + bv[ni];
        Out[(size_t)(rbase + r) * 768 + col[ni]] = f2bf(v);
        s += v * v;
      }
#pragma unroll
      for (int off = 1; off < 16; off <<= 1) s += __shfl_xor(s, off, 64);
      if (li == 0) atomicAdd(&ssq[rbase + r], s);
    }
  }
}

// ---------- scores + row-max + fused MLP tail ----------
__global__ __launch_bounds__(256) void scores_max(const unsigned short* __restrict__ Qh,
                                                  const unsigned short* __restrict__ Kh,
                                                  const float* __restrict__ kssq,
                                                  const float* __restrict__ qssq,
                                                  const int* __restrict__ pad,
                                                  const float* __restrict__ w1,
                                                  const float* __restrict__ b1,
                                                  const float* __restrict__ w2,
                                                  const float* __restrict__ b2,
                                                  unsigned* __restrict__ umax,
                                                  unsigned* __restrict__ cnt,
                                                  float* __restrict__ out) {
  const int K = 768;
  __shared__ __align__(16) unsigned short sA[2][128 * 64];
  __shared__ __align__(16) unsigned short sB[2][128 * 64];
  __shared__ int sTicket;
  // batch -> XCD pinning: id&7 == batch&7 (3MB working set per batch in one L2)
  int id = blockIdx.x;                 // 0..1023
  int x = id & 7, g = id >> 3;
  int tile = g & 63;
  int qt = tile & 7, kt_ = tile >> 3;
  int b = ((g >> 6) << 3) | x;

  const int t = threadIdx.x;
  const int lane = t & 63, w = t >> 6;
  const int wr = w >> 1, wc = w & 1;
  const unsigned short* Ab = Qh + ((size_t)b * 1024 + qt * 128) * K;
  const unsigned short* Bb = Kh + ((size_t)b * 1024 + kt_ * 128) * K;
  f32x4 acc[4][4] = {};
  const int srow = t >> 3;
  const int scol = (t & 7) * 8;
  const int hsw = scol ^ ((srow & 7) << 3);
  const int lg = lane >> 4, li = lane & 15;

  // prologue
#pragma unroll
  for (int s = 0; s < 4; ++s) {
    int row = srow + s * 32;
    gload16(Ab + (size_t)row * K + hsw, (char*)sA[0] + t * 16 + s * 4096);
    gload16(Bb + (size_t)row * K + hsw, (char*)sB[0] + t * 16 + s * 4096);
  }
  __syncthreads();

  for (int kt = 0; kt < 12; ++kt) {
    const int cur = kt & 1;
    const unsigned short* cA = sA[cur];
    const unsigned short* cB = sB[cur];
    if (kt < 11) {
      const int k0n = (kt + 1) * 64;
#pragma unroll
      for (int s = 0; s < 4; ++s) {
        int row = srow + s * 32;
        gload16(Ab + (size_t)row * K + k0n + hsw, (char*)sA[cur ^ 1] + t * 16 + s * 4096);
        gload16(Bb + (size_t)row * K + k0n + hsw, (char*)sB[cur ^ 1] + t * 16 + s * 4096);
      }
    }
#pragma unroll
    for (int ks = 0; ks < 2; ++ks) {
      s16x8 af[4], bfr[4];
#pragma unroll
      for (int mi = 0; mi < 4; ++mi) {
        int row = wr * 64 + mi * 16 + li;
        af[mi] = *(const s16x8*)(cA + row * 64 + ((ks * 32 + lg * 8) ^ ((row & 7) << 3)));
      }
#pragma unroll
      for (int ni = 0; ni < 4; ++ni) {
        int row = wc * 64 + ni * 16 + li;
        bfr[ni] = *(const s16x8*)(cB + row * 64 + ((ks * 32 + lg * 8) ^ ((row & 7) << 3)));
      }
#pragma unroll
      for (int mi = 0; mi < 4; ++mi)
#pragma unroll
        for (int ni = 0; ni < 4; ++ni)
          acc[mi][ni] = __builtin_amdgcn_mfma_f32_16x16x32_bf16(af[mi], bfr[ni], acc[mi][ni], 0, 0, 0);
    }
    __syncthreads();
  }
  // epilogue: 1/||k|| col scaling, pad mask, row max, atomicMax (enc2)
  float rk[4]; bool valid[4];
#pragma unroll
  for (int ni = 0; ni < 4; ++ni) {
    int gcol = b * 1024 + kt_ * 128 + wc * 64 + ni * 16 + li;
    rk[ni] = 1.0f / fmaxf(sqrtf(kssq[gcol]), 1e-8f);
    valid[ni] = (pad[gcol] == 0);
  }
#pragma unroll
  for (int mi = 0; mi < 4; ++mi) {
#pragma unroll
    for (int r = 0; r < 4; ++r) {
      float v = -INFINITY;
#pragma unroll
      for (int ni = 0; ni < 4; ++ni)
        if (valid[ni]) v = fmaxf(v, acc[mi][ni][r] * rk[ni]);
#pragma unroll
      for (int off = 1; off < 16; off <<= 1) v = fmaxf(v, __shfl_xor(v, off, 64));
      if (li == 0) {
        int row = b * 1024 + qt * 128 + wr * 64 + mi * 16 + lg * 4 + r;
        unsigned e = fenc2(v);
        if (e) atomicMax(&umax[row], e);
      }
    }
  }
  // completion ticket: last of the 8 kt-blocks for (b,qt) runs the MLP tail
  __threadfence();
  __syncthreads();
  if (t == 0) sTicket = (int)atomicAdd(&cnt[b * 8 + qt], 1u);
  __syncthreads();
  if (sTicket == 7) {
    __threadfence();
    if (t < 128) {
      int row = b * 1024 + qt * 128 + t;
      unsigned u = atomicAdd(&umax[row], 0u);   // coherent cross-XCD read
      float m = fdec2(u) / fmaxf(sqrtf(qssq[row]), 1e-8f);
      float s = b2[0];
#pragma unroll
      for (int jj = 0; jj < 16; ++jj) s += w2[jj] * fmaxf(m * w1[jj] + b1[jj], 0.f);
      out[row] = 1.f / (1.f + expf(-s));
    }
  }
}

// ---------- host ----------
extern "C" void kernel_launch(void* const* d_in, const int* in_sizes, int n_in,
                              void* d_out, int out_size, void* d_ws, size_t ws_size,
                              hipStream_t stream) {
  const float* image = (const float*)d_in[0];   // [16,32,32,768]
  const float* text  = (const float*)d_in[1];   // [16,1024,768]
  const int*   pad   = (const int*)d_in[2];     // [16,32,32]
  const float* Wq    = (const float*)d_in[3];
  const float* bq    = (const float*)d_in[4];
  const float* Wk    = (const float*)d_in[5];
  const float* bk    = (const float*)d_in[6];
  const float* W1    = (const float*)d_in[7];
  const float* b1    = (const float*)d_in[8];
  const float* W2    = (const float*)d_in[9];
  const float* b2    = (const float*)d_in[10];
  float* out = (float*)d_out;

  char* ws = (char*)d_ws;
  unsigned*       um  = (unsigned*)(ws);                  // 65536 B
  float*          qss = (float*)(ws + 65536);             // 65536 B
  float*          kss = (float*)(ws + 131072);            // 65536 B
  unsigned*       cnt = (unsigned*)(ws + 196608);         // 512 B (pad to 262144)
  unsigned short* Qh  = (unsigned short*)(ws + 262144);   // 25165824 B
  unsigned short* Kh  = (unsigned short*)(ws + 262144 + 25165824);
  unsigned short* Wqb = (unsigned short*)(ws + 262144 + 50331648);
  unsigned short* Wkb = (unsigned short*)(ws + 262144 + 51511296);

  hipMemsetAsync(ws, 0, 262144, stream);   // umax=enc2(-inf)=0, ssq=0, cnt=0
  cvt2<<<1152, 256, 0, stream>>>(Wq, Wk, Wqb, Wkb, 147456);
  proj<<<dim3(768, 1, 2), 256, 0, stream>>>(text, image, Wqb, Wkb, bq, bk, Qh, Kh, qss, kss);
  scores_max<<<1024, 256, 0, stream>>>(Qh, Kh, kss, qss, pad, W1, b1, W2, b2, um, cnt, out);
}

// Round 5
// 251.138 us; speedup vs baseline: 1.3011x; 1.3011x over previous
//
#include <hip/hip_runtime.h>
#include <math.h>

typedef float  f32x4 __attribute__((ext_vector_type(4)));
typedef short  s16x8 __attribute__((ext_vector_type(8)));
typedef unsigned short u16x4 __attribute__((ext_vector_type(4)));
typedef unsigned short u16x8 __attribute__((ext_vector_type(8)));

// ---------- helpers ----------
__device__ __forceinline__ unsigned short f2bf(float f) {
  unsigned u = __float_as_uint(f);
  u += 0x7FFFu + ((u >> 16) & 1u);   // round-to-nearest-even
  return (unsigned short)(u >> 16);
}
// monotone float->uint encoding, biased so enc2(-inf)==0 (memset-friendly)
__device__ __forceinline__ unsigned fenc2(float f) {
  unsigned u = __float_as_uint(f);
  u = (u & 0x80000000u) ? ~u : (u | 0x80000000u);
  return u - 0x007FFFFFu;
}
__device__ __forceinline__ float fdec2(unsigned u) {
  u += 0x007FFFFFu;
  u = (u & 0x80000000u) ? (u & 0x7FFFFFFFu) : ~u;
  return __uint_as_float(u);
}
__device__ __forceinline__ void gload16(const void* g, void* l) {
  __builtin_amdgcn_global_load_lds(
      (const __attribute__((address_space(1))) unsigned int*)g,
      (__attribute__((address_space(3))) unsigned int*)l, 16, 0, 0);
}

// ---------- weights f32 -> bf16 (both in one launch) ----------
__global__ __launch_bounds__(256) void cvt2(const float* __restrict__ a,
                                            const float* __restrict__ b,
                                            unsigned short* __restrict__ da,
                                            unsigned short* __restrict__ db, int n4) {
  int i = blockIdx.x * 256 + threadIdx.x;
  int stride = gridDim.x * 256;
  for (; i < 2 * n4; i += stride) {
    const float* s = (i < n4) ? a : b;
    unsigned short* d = (i < n4) ? da : db;
    int j = (i < n4) ? i : i - n4;
    f32x4 v = ((const f32x4*)s)[j];
    u16x4 o;
    o[0] = f2bf(v[0]); o[1] = f2bf(v[1]); o[2] = f2bf(v[2]); o[3] = f2bf(v[3]);
    ((u16x4*)d)[j] = o;
  }
}

// ---------- proj: Out = bf16(Xf32 @ W^T + bias), ssq[row] += sum of squares ----------
// Asymmetric pipeline: A (f32) reg-hoisted one tile ahead (issue-early/write-late,
// single 16KB LDS buffer); B (bf16 weights) 2-deep global_load_lds dbuf (32KB).
// 48KB LDS total -> 3 blocks/CU. Two barriers per K-step; both staging latencies
// hidden under the MFMA phase.
__global__ __launch_bounds__(256) void proj(const float* __restrict__ Xq,
                                            const float* __restrict__ Xk,
                                            const unsigned short* __restrict__ Wqb,
                                            const unsigned short* __restrict__ Wkb,
                                            const float* __restrict__ bq,
                                            const float* __restrict__ bk,
                                            unsigned short* __restrict__ Qh,
                                            unsigned short* __restrict__ Kh,
                                            float* __restrict__ qssq,
                                            float* __restrict__ kssq) {
  const int K = 768;
  __shared__ __align__(16) unsigned short sA[128 * 64];      // 16 KB, single
  __shared__ __align__(16) unsigned short sB[2][128 * 64];   // 32 KB, dbuf
  int id = blockIdx.x;                 // 0..767
  int xcd = id & 7, j = id >> 3;       // j: 0..95
  int by = j % 6, bxl = j / 6;         // by 0..5, bxl 0..15
  int bx = xcd * 16 + bxl;             // 0..127
  const float* A; const unsigned short* Bw; const float* bias;
  unsigned short* Out; float* ssq;
  if (blockIdx.z == 0) { A = Xq; Bw = Wqb; bias = bq; Out = Qh; ssq = qssq; }
  else                 { A = Xk; Bw = Wkb; bias = bk; Out = Kh; ssq = kssq; }

  const int t = threadIdx.x;
  const int lane = t & 63, w = t >> 6;
  const int wr = w >> 1, wc = w & 1;
  const int m0 = bx * 128, n0 = by * 128;
  const float* Ab = A + (size_t)m0 * K;
  const unsigned short* Bb = Bw + (size_t)n0 * K;
  f32x4 acc[4][4] = {};
  const int srow = t >> 3;             // 0..31
  const int scol = (t & 7) * 8;        // halfword col offset in 64
  const int hsw = scol ^ ((srow & 7) << 3);
  const int lg = lane >> 4, li = lane & 15;

  // prologue: stage tile 0 (B -> sB[0] async; A -> regs -> cvt -> sA)
#pragma unroll
  for (int s = 0; s < 4; ++s) {
    int row = srow + s * 32;
    gload16(Bb + (size_t)row * K + hsw, (char*)sB[0] + t * 16 + s * 4096);
  }
  {
    f32x4 q0[4], q1[4];
#pragma unroll
    for (int s = 0; s < 4; ++s) {
      const float* src = Ab + (size_t)(srow + s * 32) * K + scol;
      q0[s] = *(const f32x4*)src; q1[s] = *(const f32x4*)(src + 4);
    }
#pragma unroll
    for (int s = 0; s < 4; ++s) {
      int row = srow + s * 32;
      u16x8 o;
      o[0] = f2bf(q0[s][0]); o[1] = f2bf(q0[s][1]); o[2] = f2bf(q0[s][2]); o[3] = f2bf(q0[s][3]);
      o[4] = f2bf(q1[s][0]); o[5] = f2bf(q1[s][1]); o[6] = f2bf(q1[s][2]); o[7] = f2bf(q1[s][3]);
      *(u16x8*)(sA + row * 64 + (scol ^ ((row & 7) << 3))) = o;
    }
  }
  __syncthreads();   // drains B(0) vmcnt + A(0) lgkm

  for (int kt = 0; kt < 12; ++kt) {
    const int cur = kt & 1;
    const bool pre = (kt < 11);
    f32x4 p0[4], p1[4];
    if (pre) {
      const int k0n = (kt + 1) * 64;
      // issue next B tile into the other LDS buffer (lands during compute)
#pragma unroll
      for (int s = 0; s < 4; ++s) {
        int row = srow + s * 32;
        gload16(Bb + (size_t)row * K + k0n + hsw, (char*)sB[cur ^ 1] + t * 16 + s * 4096);
      }
      // issue next A tile into registers (lands during compute)
#pragma unroll
      for (int s = 0; s < 4; ++s) {
        const float* src = Ab + (size_t)(srow + s * 32) * K + k0n + scol;
        p0[s] = *(const f32x4*)src; p1[s] = *(const f32x4*)(src + 4);
      }
    }
    // compute tile kt from sA, sB[cur]
#pragma unroll
    for (int ks = 0; ks < 2; ++ks) {
      s16x8 af[4], bfr[4];
#pragma unroll
      for (int mi = 0; mi < 4; ++mi) {
        int row = wr * 64 + mi * 16 + li;
        af[mi] = *(const s16x8*)(sA + row * 64 + ((ks * 32 + lg * 8) ^ ((row & 7) << 3)));
      }
#pragma unroll
      for (int ni = 0; ni < 4; ++ni) {
        int row = wc * 64 + ni * 16 + li;
        bfr[ni] = *(const s16x8*)(sB[cur] + row * 64 + ((ks * 32 + lg * 8) ^ ((row & 7) << 3)));
      }
#pragma unroll
      for (int mi = 0; mi < 4; ++mi)
#pragma unroll
        for (int ni = 0; ni < 4; ++ni)
          acc[mi][ni] = __builtin_amdgcn_mfma_f32_16x16x32_bf16(af[mi], bfr[ni], acc[mi][ni], 0, 0, 0);
    }
    __syncthreads();   // all waves done reading sA(kt); B(kt+1)/A-regs landed
    if (pre) {
#pragma unroll
      for (int s = 0; s < 4; ++s) {
        int row = srow + s * 32;
        u16x8 o;
        o[0] = f2bf(p0[s][0]); o[1] = f2bf(p0[s][1]); o[2] = f2bf(p0[s][2]); o[3] = f2bf(p0[s][3]);
        o[4] = f2bf(p1[s][0]); o[5] = f2bf(p1[s][1]); o[6] = f2bf(p1[s][2]); o[7] = f2bf(p1[s][3]);
        *(u16x8*)(sA + row * 64 + (scol ^ ((row & 7) << 3))) = o;
      }
      __syncthreads(); // sA(kt+1) visible
    }
  }
  // epilogue: bias, bf16 store, per-row sum-of-squares -> atomicAdd
  float bv[4]; int col[4];
#pragma unroll
  for (int ni = 0; ni < 4; ++ni) { col[ni] = n0 + wc * 64 + ni * 16 + li; bv[ni] = bias[col[ni]]; }
#pragma unroll
  for (int mi = 0; mi < 4; ++mi) {
    int rbase = m0 + wr * 64 + mi * 16 + lg * 4;
#pragma unroll
    for (int r = 0; r < 4; ++r) {
      float s = 0.f;
#pragma unroll
      for (int ni = 0; ni < 4; ++ni) {
        float v = acc[mi][ni][r] + bv[ni];
        Out[(size_t)(rbase + r) * 768 + col[ni]] = f2bf(v);
        s += v * v;
      }
#pragma unroll
      for (int off = 1; off < 16; off <<= 1) s += __shfl_xor(s, off, 64);
      if (li == 0) atomicAdd(&ssq[rbase + r], s);
    }
  }
}

// ---------- scores: raw Q.K MFMA; epilogue scales by 1/||k||, masks, row-max ----------
// (round-3 proven structure: single-buffer 32KB, 2 barriers/K-step)
__global__ __launch_bounds__(256) void scores_max(const unsigned short* __restrict__ Qh,
                                                  const unsigned short* __restrict__ Kh,
                                                  const float* __restrict__ kssq,
                                                  const int* __restrict__ pad,
                                                  unsigned* __restrict__ umax) {
  const int K = 768;
  __shared__ __align__(16) unsigned short sA[128 * 64];
  __shared__ __align__(16) unsigned short sB[128 * 64];
  // batch -> XCD pinning: id&7 == batch&7
  int id = blockIdx.x;                 // 0..1023
  int x = id & 7, g = id >> 3;
  int tile = g & 63;
  int qt = tile & 7, kt_ = tile >> 3;
  int b = ((g >> 6) << 3) | x;

  const int t = threadIdx.x;
  const int lane = t & 63, w = t >> 6;
  const int wr = w >> 1, wc = w & 1;
  const unsigned short* Ab = Qh + ((size_t)b * 1024 + qt * 128) * K;
  const unsigned short* Bb = Kh + ((size_t)b * 1024 + kt_ * 128) * K;
  f32x4 acc[4][4] = {};
  const int srow = t >> 3;
  const int scol = (t & 7) * 8;
  const int hsw = scol ^ ((srow & 7) << 3);
  const int lg = lane >> 4, li = lane & 15;

  for (int k0 = 0; k0 < K; k0 += 64) {
#pragma unroll
    for (int s = 0; s < 4; ++s) {
      int row = srow + s * 32;
      gload16(Ab + (size_t)row * K + k0 + hsw, (char*)sA + t * 16 + s * 4096);
      gload16(Bb + (size_t)row * K + k0 + hsw, (char*)sB + t * 16 + s * 4096);
    }
    __syncthreads();
#pragma unroll
    for (int ks = 0; ks < 2; ++ks) {
      s16x8 af[4], bfr[4];
#pragma unroll
      for (int mi = 0; mi < 4; ++mi) {
        int row = wr * 64 + mi * 16 + li;
        af[mi] = *(const s16x8*)(sA + row * 64 + ((ks * 32 + lg * 8) ^ ((row & 7) << 3)));
      }
#pragma unroll
      for (int ni = 0; ni < 4; ++ni) {
        int row = wc * 64 + ni * 16 + li;
        bfr[ni] = *(const s16x8*)(sB + row * 64 + ((ks * 32 + lg * 8) ^ ((row & 7) << 3)));
      }
#pragma unroll
      for (int mi = 0; mi < 4; ++mi)
#pragma unroll
        for (int ni = 0; ni < 4; ++ni)
          acc[mi][ni] = __builtin_amdgcn_mfma_f32_16x16x32_bf16(af[mi], bfr[ni], acc[mi][ni], 0, 0, 0);
    }
    __syncthreads();
  }
  float rk[4]; bool valid[4];
#pragma unroll
  for (int ni = 0; ni < 4; ++ni) {
    int gcol = b * 1024 + kt_ * 128 + wc * 64 + ni * 16 + li;
    rk[ni] = 1.0f / fmaxf(sqrtf(kssq[gcol]), 1e-8f);
    valid[ni] = (pad[gcol] == 0);
  }
#pragma unroll
  for (int mi = 0; mi < 4; ++mi) {
#pragma unroll
    for (int r = 0; r < 4; ++r) {
      float v = -INFINITY;
#pragma unroll
      for (int ni = 0; ni < 4; ++ni)
        if (valid[ni]) v = fmaxf(v, acc[mi][ni][r] * rk[ni]);
#pragma unroll
      for (int off = 1; off < 16; off <<= 1) v = fmaxf(v, __shfl_xor(v, off, 64));
      if (li == 0) {
        int row = b * 1024 + qt * 128 + wr * 64 + mi * 16 + lg * 4 + r;
        unsigned e = fenc2(v);
        if (e) atomicMax(&umax[row], e);
      }
    }
  }
}

// ---------- tiny MLP: out = sigmoid(relu((max/||q||)*W1+b1) @ W2 + b2) ----------
__global__ __launch_bounds__(256) void mlp_kernel(const unsigned* __restrict__ umax,
                                                  const float* __restrict__ qssq,
                                                  const float* __restrict__ w1,
                                                  const float* __restrict__ b1,
                                                  const float* __restrict__ w2,
                                                  const float* __restrict__ b2,
                                                  float* __restrict__ out, int n) {
  int i = blockIdx.x * 256 + threadIdx.x;
  if (i >= n) return;
  float m = fdec2(umax[i]) / fmaxf(sqrtf(qssq[i]), 1e-8f);
  float s = b2[0];
#pragma unroll
  for (int j = 0; j < 16; ++j) s += w2[j] * fmaxf(m * w1[j] + b1[j], 0.f);
  out[i] = 1.f / (1.f + expf(-s));
}

// ---------- host ----------
extern "C" void kernel_launch(void* const* d_in, const int* in_sizes, int n_in,
                              void* d_out, int out_size, void* d_ws, size_t ws_size,
                              hipStream_t stream) {
  const float* image = (const float*)d_in[0];   // [16,32,32,768]
  const float* text  = (const float*)d_in[1];   // [16,1024,768]
  const int*   pad   = (const int*)d_in[2];     // [16,32,32]
  const float* Wq    = (const float*)d_in[3];
  const float* bq    = (const float*)d_in[4];
  const float* Wk    = (const float*)d_in[5];
  const float* bk    = (const float*)d_in[6];
  const float* W1    = (const float*)d_in[7];
  const float* b1    = (const float*)d_in[8];
  const float* W2    = (const float*)d_in[9];
  const float* b2    = (const float*)d_in[10];
  float* out = (float*)d_out;

  char* ws = (char*)d_ws;
  unsigned*       um  = (unsigned*)(ws);                  // 65536 B
  float*          qss = (float*)(ws + 65536);             // 65536 B
  float*          kss = (float*)(ws + 131072);            // 65536 B
  unsigned short* Qh  = (unsigned short*)(ws + 262144);   // 25165824 B
  unsigned short* Kh  = (unsigned short*)(ws + 262144 + 25165824);
  unsigned short* Wqb = (unsigned short*)(ws + 262144 + 50331648);
  unsigned short* Wkb = (unsigned short*)(ws + 262144 + 51511296);

  hipMemsetAsync(ws, 0, 196608, stream);   // umax=enc2(-inf)=0, qss=0, kss=0
  cvt2<<<1152, 256, 0, stream>>>(Wq, Wk, Wqb, Wkb, 147456);
  proj<<<dim3(768, 1, 2), 256, 0, stream>>>(text, image, Wqb, Wkb, bq, bk, Qh, Kh, qss, kss);
  scores_max<<<1024, 256, 0, stream>>>(Qh, Kh, kss, pad, um);
  mlp_kernel<<<64, 256, 0, stream>>>(um, qss, W1, b1, W2, b2, out, 16384);
}